// Round 1
// baseline (377.874 us; speedup 1.0000x reference)
//
#include <hip/hip_runtime.h>
#include <stdint.h>

#define N_NODES 50000
#define DD 256
#define SS 25

typedef unsigned short u16;
typedef __attribute__((ext_vector_type(8))) __bf16 bf16x8;
typedef __attribute__((ext_vector_type(4))) float f32x4;

__device__ __forceinline__ float bf2f(u16 u) {
    union { uint32_t i; float f; } c;
    c.i = ((uint32_t)u) << 16;
    return c.f;
}
__device__ __forceinline__ u16 f2bf(float f) {  // round-to-nearest-even
    union { float f; uint32_t i; } c;
    c.f = f;
    uint32_t r = c.i + 0x7fffu + ((c.i >> 16) & 1u);
    return (u16)(r >> 16);
}

// ---- f32 -> bf16 elementwise (exact: grid*block*4 == n) ----
__global__ __launch_bounds__(256) void cvt_f32_bf16_k(const float4* __restrict__ in,
                                                      u16* __restrict__ out) {
    int i = blockIdx.x * 256 + threadIdx.x;
    float4 v = in[i];
    uint2 o;
    o.x = (uint32_t)f2bf(v.x) | ((uint32_t)f2bf(v.y) << 16);
    o.y = (uint32_t)f2bf(v.z) | ((uint32_t)f2bf(v.w) << 16);
    *reinterpret_cast<uint2*>(out + (size_t)i * 4) = o;
}

// ---- weight f32 [K][256] -> bf16 MFMA B-fragment layout ----
// out[((kt*16 + ct)*64 + lane)*8 + e] = W[kt*32 + (lane>>4)*8 + e][ct*16 + (lane&15)]
__global__ __launch_bounds__(256) void cvt_w_k(const float* __restrict__ W,
                                               u16* __restrict__ out, int KT) {
    int t = blockIdx.x * 256 + threadIdx.x;
    if (t >= KT * 16 * 64) return;
    int lane = t & 63;
    int ct = (t >> 6) & 15;
    int kt = t >> 10;
    int k0 = kt * 32 + (lane >> 4) * 8;
    int col = ct * 16 + (lane & 15);
    u16 r[8];
#pragma unroll
    for (int e = 0; e < 8; e++) r[e] = f2bf(W[(size_t)(k0 + e) * DD + col]);
    uint4 v;
    v.x = (uint32_t)r[0] | ((uint32_t)r[1] << 16);
    v.y = (uint32_t)r[2] | ((uint32_t)r[3] << 16);
    v.z = (uint32_t)r[4] | ((uint32_t)r[5] << 16);
    v.w = (uint32_t)r[6] | ((uint32_t)r[7] << 16);
    *reinterpret_cast<uint4*>(out + (size_t)t * 8) = v;
}

// ---- gather + max-pool: agg[n][:] = max_s h[idx[n][s]][:]  (h >= 0, bf16) ----
__global__ __launch_bounds__(64) void gather_max_k(const u16* __restrict__ h,
                                                   const int* __restrict__ idx,
                                                   u16* __restrict__ agg) {
    int n = blockIdx.x;
    int t = threadIdx.x;  // 0..63, each handles 4 consecutive bf16
    __shared__ int sidx[SS];
    if (t < SS) sidx[t] = idx[(size_t)n * SS + t];
    __syncthreads();
    float m0 = 0.f, m1 = 0.f, m2 = 0.f, m3 = 0.f;  // relu output >= 0
#pragma unroll
    for (int s = 0; s < SS; s++) {
        uint2 v = *reinterpret_cast<const uint2*>(h + (size_t)sidx[s] * DD + t * 4);
        m0 = fmaxf(m0, bf2f((u16)(v.x & 0xffffu)));
        m1 = fmaxf(m1, bf2f((u16)(v.x >> 16)));
        m2 = fmaxf(m2, bf2f((u16)(v.y & 0xffffu)));
        m3 = fmaxf(m3, bf2f((u16)(v.y >> 16)));
    }
    uint2 o;
    o.x = (uint32_t)f2bf(m0) | ((uint32_t)f2bf(m1) << 16);
    o.y = (uint32_t)f2bf(m2) | ((uint32_t)f2bf(m3) << 16);
    *reinterpret_cast<uint2*>(agg + (size_t)n * DD + t * 4) = o;
}

// ---- bf16 MFMA GEMM: out[M,256] = [A1 | A2][M, 32*KT] @ Bf + bias ----
// Block: 128 rows x 128 cols, 4 waves (2x2), each wave 64x64 via 4x4 16x16x32 frags.
// LDS-free: A fragments read direct from global (rows L1/L2-served),
// B pre-laid-out in fragment order (one coalesced 16B load per lane).
template <int KT, bool RELU, bool OUTBF16>
__global__ __launch_bounds__(256) void gemm_k(const u16* __restrict__ A1,
                                              const u16* __restrict__ A2,
                                              const u16* __restrict__ Bf,
                                              const float* __restrict__ bias,
                                              u16* __restrict__ obf,
                                              float* __restrict__ of32, int M) {
    const int lane = threadIdx.x & 63;
    const int wid = threadIdx.x >> 6;
    const int wm = wid >> 1, wn = wid & 1;
    const int row_base = blockIdx.x * 128 + wm * 64;
    const int col_base = blockIdx.y * 128 + wn * 64;
    const int lr = lane & 15, lk = lane >> 4;
    const int ct0 = col_base >> 4;

    int ar[4];
#pragma unroll
    for (int m = 0; m < 4; m++) {
        int r = row_base + m * 16 + lr;
        ar[m] = (r < M) ? r : (M - 1);  // clamp: garbage only pollutes discarded rows
    }

    f32x4 acc[4][4] = {};

#pragma unroll
    for (int kt = 0; kt < KT; ++kt) {
        const u16* Ab = (KT == 16 && kt >= 8) ? A2 : A1;
        const int kk = (KT == 16 && kt >= 8) ? (kt - 8) : kt;
        bf16x8 a[4], b[4];
#pragma unroll
        for (int m = 0; m < 4; m++)
            a[m] = *reinterpret_cast<const bf16x8*>(Ab + (size_t)ar[m] * DD + kk * 32 + lk * 8);
#pragma unroll
        for (int n = 0; n < 4; n++)
            b[n] = *reinterpret_cast<const bf16x8*>(Bf + ((size_t)(kt * 16 + ct0 + n) * 64 + lane) * 8);
#pragma unroll
        for (int m = 0; m < 4; m++)
#pragma unroll
            for (int n = 0; n < 4; n++)
                acc[m][n] = __builtin_amdgcn_mfma_f32_16x16x32_bf16(a[m], b[n], acc[m][n], 0, 0, 0);
    }

#pragma unroll
    for (int n = 0; n < 4; n++) {
        const int col = col_base + n * 16 + lr;
        const float bz = bias[col];
#pragma unroll
        for (int m = 0; m < 4; m++) {
            const int r0 = row_base + m * 16 + lk * 4;
#pragma unroll
            for (int e = 0; e < 4; e++) {
                const int r = r0 + e;
                if (r < M) {
                    float v = acc[m][n][e] + bz;
                    if (RELU) v = fmaxf(v, 0.0f);
                    if (OUTBF16)
                        obf[(size_t)r * DD + col] = f2bf(v);
                    else
                        of32[(size_t)r * DD + col] = v;
                }
            }
        }
    }
}

extern "C" void kernel_launch(void* const* d_in, const int* in_sizes, int n_in,
                              void* d_out, int out_size, void* d_ws, size_t ws_size,
                              hipStream_t stream) {
    const float* features = (const float*)d_in[0];
    const int* neigh = (const int*)d_in[1];
    const float* Wp0 = (const float*)d_in[2];
    const float* bp0 = (const float*)d_in[3];
    const float* Wfc0 = (const float*)d_in[4];
    const float* bfc0 = (const float*)d_in[5];
    const float* Wp1 = (const float*)d_in[6];
    const float* bp1 = (const float*)d_in[7];
    const float* Wfc1 = (const float*)d_in[8];
    const float* bfc1 = (const float*)d_in[9];
    float* out = (float*)d_out;

    // ws carve (bf16 elements): 3 big ping-pong buffers + 4 fragment-layout weights
    const size_t ND = (size_t)N_NODES * DD;  // 12.8M
    u16* Xb = (u16*)d_ws;          // current-layer input (bf16)
    u16* Hb = Xb + ND;             // h buffer; reused as layer-0 output
    u16* Agg = Hb + ND;            // max-pooled neighbor features
    u16* Wpb0 = Agg + ND;          // 8*16*64*8  = 65536
    u16* Wfb0 = Wpb0 + 65536;      // 16*16*64*8 = 131072
    u16* Wpb1 = Wfb0 + 131072;
    u16* Wfb1 = Wpb1 + 65536;
    // total = (3*12.8M + 393216) * 2B ≈ 74 MB

    // weight + feature conversion
    cvt_w_k<<<32, 256, 0, stream>>>(Wp0, Wpb0, 8);
    cvt_w_k<<<64, 256, 0, stream>>>(Wfc0, Wfb0, 16);
    cvt_w_k<<<32, 256, 0, stream>>>(Wp1, Wpb1, 8);
    cvt_w_k<<<64, 256, 0, stream>>>(Wfc1, Wfb1, 16);
    cvt_f32_bf16_k<<<12500, 256, 0, stream>>>((const float4*)features, Xb);  // 12500*256*4 == N*D

    dim3 gg((N_NODES + 127) / 128, 2);

    // ---- layer 0 ----
    gemm_k<8, true, true><<<gg, 256, 0, stream>>>(Xb, nullptr, Wpb0, bp0, Hb, nullptr, N_NODES);
    gather_max_k<<<N_NODES, 64, 0, stream>>>(Hb, neigh, Agg);
    // h (Hb) is dead after the gather -> GEMM2 writes layer-0 output into Hb
    gemm_k<16, true, true><<<gg, 256, 0, stream>>>(Xb, Agg, Wfb0, bfc0, Hb, nullptr, N_NODES);

    // ---- layer 1 ---- (Xb = features is dead now; reuse for h1)
    gemm_k<8, true, true><<<gg, 256, 0, stream>>>(Hb, nullptr, Wpb1, bp1, Xb, nullptr, N_NODES);
    gather_max_k<<<N_NODES, 64, 0, stream>>>(Xb, neigh, Agg);
    gemm_k<16, false, false><<<gg, 256, 0, stream>>>(Hb, Agg, Wfb1, bfc1, nullptr, out, N_NODES);
}

// Round 2
// 328.494 us; speedup vs baseline: 1.1503x; 1.1503x over previous
//
#include <hip/hip_runtime.h>
#include <stdint.h>

#define N_NODES 50000
#define DD 256
#define SS 25

typedef unsigned short u16;
typedef __attribute__((ext_vector_type(8))) __bf16 bf16x8;
typedef __attribute__((ext_vector_type(4))) float f32x4;

__device__ __forceinline__ float bf2f(u16 u) {
    union { uint32_t i; float f; } c;
    c.i = ((uint32_t)u) << 16;
    return c.f;
}
__device__ __forceinline__ u16 f2bf(float f) {  // round-to-nearest-even
    union { float f; uint32_t i; } c;
    c.f = f;
    uint32_t r = c.i + 0x7fffu + ((c.i >> 16) & 1u);
    return (u16)(r >> 16);
}

__device__ __forceinline__ void gld16(void* lds, const void* g) {
    __builtin_amdgcn_global_load_lds(
        (const __attribute__((address_space(1))) uint32_t*)g,
        (__attribute__((address_space(3))) uint32_t*)lds, 16, 0, 0);
}

// ---- f32 -> bf16 elementwise (exact: grid*block*4 == n) ----
__global__ __launch_bounds__(256) void cvt_f32_bf16_k(const float4* __restrict__ in,
                                                      u16* __restrict__ out) {
    int i = blockIdx.x * 256 + threadIdx.x;
    float4 v = in[i];
    uint2 o;
    o.x = (uint32_t)f2bf(v.x) | ((uint32_t)f2bf(v.y) << 16);
    o.y = (uint32_t)f2bf(v.z) | ((uint32_t)f2bf(v.w) << 16);
    *reinterpret_cast<uint2*>(out + (size_t)i * 4) = o;
}

// ---- weight f32 [K][256] -> bf16 MFMA B-fragment layout ----
// out[((kt*16 + ct)*64 + lane)*8 + e] = W[kt*32 + (lane>>4)*8 + e][ct*16 + (lane&15)]
__global__ __launch_bounds__(256) void cvt_w_k(const float* __restrict__ W,
                                               u16* __restrict__ out, int KT) {
    int t = blockIdx.x * 256 + threadIdx.x;
    if (t >= KT * 16 * 64) return;
    int lane = t & 63;
    int ct = (t >> 6) & 15;
    int kt = t >> 10;
    int k0 = kt * 32 + (lane >> 4) * 8;
    int col = ct * 16 + (lane & 15);
    u16 r[8];
#pragma unroll
    for (int e = 0; e < 8; e++) r[e] = f2bf(W[(size_t)(k0 + e) * DD + col]);
    uint4 v;
    v.x = (uint32_t)r[0] | ((uint32_t)r[1] << 16);
    v.y = (uint32_t)r[2] | ((uint32_t)r[3] << 16);
    v.z = (uint32_t)r[4] | ((uint32_t)r[5] << 16);
    v.w = (uint32_t)r[6] | ((uint32_t)r[7] << 16);
    *reinterpret_cast<uint4*>(out + (size_t)t * 8) = v;
}

// ---- gather + max-pool: agg[n][:] = max_s h[idx[n][s]][:]  (h >= 0, bf16) ----
// 4 nodes/block (one per wave); 16B/lane loads, 2 samples across lane halves.
__global__ __launch_bounds__(256) void gather_max_k(const u16* __restrict__ h,
                                                    const int* __restrict__ idx,
                                                    u16* __restrict__ agg) {
    const int wid = threadIdx.x >> 6;
    const int lane = threadIdx.x & 63;
    const int n = blockIdx.x * 4 + wid;
    __shared__ int sidx[4][28];
    if (lane < SS) sidx[wid][lane] = idx[(size_t)n * SS + lane];
    __syncthreads();
    const int half = lane >> 5;
    const int c8 = lane & 31;  // 8 consecutive bf16 = 16B chunk
    float m[8];
#pragma unroll
    for (int j = 0; j < 8; j++) m[j] = 0.0f;  // relu output >= 0
#pragma unroll
    for (int s = 0; s < SS; s += 2) {
        int sp = s + half;
        if (sp >= SS) sp = SS - 1;
        const int r = sidx[wid][sp];
        uint4 v = *reinterpret_cast<const uint4*>(h + (size_t)r * DD + c8 * 8);
        m[0] = fmaxf(m[0], bf2f((u16)(v.x & 0xffffu)));
        m[1] = fmaxf(m[1], bf2f((u16)(v.x >> 16)));
        m[2] = fmaxf(m[2], bf2f((u16)(v.y & 0xffffu)));
        m[3] = fmaxf(m[3], bf2f((u16)(v.y >> 16)));
        m[4] = fmaxf(m[4], bf2f((u16)(v.z & 0xffffu)));
        m[5] = fmaxf(m[5], bf2f((u16)(v.z >> 16)));
        m[6] = fmaxf(m[6], bf2f((u16)(v.w & 0xffffu)));
        m[7] = fmaxf(m[7], bf2f((u16)(v.w >> 16)));
    }
#pragma unroll
    for (int j = 0; j < 8; j++) m[j] = fmaxf(m[j], __shfl_xor(m[j], 32));
    if (half == 0) {
        uint4 o;
        o.x = (uint32_t)f2bf(m[0]) | ((uint32_t)f2bf(m[1]) << 16);
        o.y = (uint32_t)f2bf(m[2]) | ((uint32_t)f2bf(m[3]) << 16);
        o.z = (uint32_t)f2bf(m[4]) | ((uint32_t)f2bf(m[5]) << 16);
        o.w = (uint32_t)f2bf(m[6]) | ((uint32_t)f2bf(m[7]) << 16);
        *reinterpret_cast<uint4*>(agg + (size_t)n * DD + c8 * 8) = o;
    }
}

// ---- bf16 MFMA GEMM: out[M,256] = [A1 | A2][M, 32*KT] @ Bf + bias ----
// 128x128 tile, 4 waves (2x2), double-buffered LDS, global_load_lds width 16.
// A LDS layout: k-group-major [lk][128 rows][8] -> conflict-free ds_read_b128
// (permutation applied on the per-lane global source address; LDS dest linear).
// B staged in fragment order (contiguous both sides).
template <int KT, bool RELU, bool OUTBF16>
__global__ __launch_bounds__(256) void gemm_k(const u16* __restrict__ A1,
                                              const u16* __restrict__ A2,
                                              const u16* __restrict__ Bf,
                                              const float* __restrict__ bias,
                                              u16* __restrict__ obf,
                                              float* __restrict__ of32, int M) {
    __shared__ u16 sAB[2][8192];  // per buf: A [0,4096), B [4096,8192)
    const int lane = threadIdx.x & 63;
    const int w = threadIdx.x >> 6;
    const int wm = w >> 1, wn = w & 1;
    const int row_base = blockIdx.x * 128;
    const int ct0b = blockIdx.y * 8;  // block's first 16-col fragment
    const int lr = lane & 15, lk = lane >> 4;

    f32x4 acc[4][4] = {};

    auto stage = [&](int buf, int kt) {
        const u16* Ab = (KT == 16 && kt >= 8) ? A2 : A1;
        const int kk = kt & 7;
#pragma unroll
        for (int j = 0; j < 2; ++j) {
            int row = row_base + j * 64 + lane;
            if (row >= M) row = M - 1;  // duplicate rows; discarded on store
            const u16* srcA = Ab + (size_t)row * DD + kk * 32 + w * 8;
            gld16(&sAB[buf][(w * 2 + j) * 512 + lane * 8], srcA);
        }
#pragma unroll
        for (int j = 0; j < 2; ++j) {
            const int nl = w * 2 + j;
            const u16* srcB = Bf + ((size_t)(kt * 16 + ct0b + nl) * 64 + lane) * 8;
            gld16(&sAB[buf][4096 + nl * 512 + lane * 8], srcB);
        }
    };

    auto compute = [&](int buf) {
        bf16x8 a[4], b[4];
#pragma unroll
        for (int m = 0; m < 4; m++)
            a[m] = *reinterpret_cast<const bf16x8*>(
                &sAB[buf][lk * 1024 + (wm * 64 + m * 16 + lr) * 8]);
#pragma unroll
        for (int n = 0; n < 4; n++)
            b[n] = *reinterpret_cast<const bf16x8*>(
                &sAB[buf][4096 + (wn * 4 + n) * 512 + lane * 8]);
#pragma unroll
        for (int m = 0; m < 4; m++)
#pragma unroll
            for (int n = 0; n < 4; n++)
                acc[m][n] = __builtin_amdgcn_mfma_f32_16x16x32_bf16(a[m], b[n], acc[m][n], 0, 0, 0);
    };

    stage(0, 0);
    asm volatile("s_waitcnt vmcnt(0)" ::: "memory");
    __syncthreads();
    int buf = 0;
#pragma unroll
    for (int kt = 0; kt < KT - 1; ++kt) {
        stage(buf ^ 1, kt + 1);  // issue next-tile loads first (overlap)
        compute(buf);
        asm volatile("s_waitcnt vmcnt(0)" ::: "memory");
        __syncthreads();
        buf ^= 1;
    }
    compute(buf);

    const int col_base = blockIdx.y * 128 + wn * 64;
#pragma unroll
    for (int n = 0; n < 4; n++) {
        const int col = col_base + n * 16 + lr;
        const float bz = bias[col];
#pragma unroll
        for (int m = 0; m < 4; m++) {
            const int r0 = row_base + wm * 64 + m * 16 + lk * 4;
#pragma unroll
            for (int e = 0; e < 4; e++) {
                const int r = r0 + e;
                if (r < M) {
                    float v = acc[m][n][e] + bz;
                    if (RELU) v = fmaxf(v, 0.0f);
                    if (OUTBF16)
                        obf[(size_t)r * DD + col] = f2bf(v);
                    else
                        of32[(size_t)r * DD + col] = v;
                }
            }
        }
    }
}

extern "C" void kernel_launch(void* const* d_in, const int* in_sizes, int n_in,
                              void* d_out, int out_size, void* d_ws, size_t ws_size,
                              hipStream_t stream) {
    const float* features = (const float*)d_in[0];
    const int* neigh = (const int*)d_in[1];
    const float* Wp0 = (const float*)d_in[2];
    const float* bp0 = (const float*)d_in[3];
    const float* Wfc0 = (const float*)d_in[4];
    const float* bfc0 = (const float*)d_in[5];
    const float* Wp1 = (const float*)d_in[6];
    const float* bp1 = (const float*)d_in[7];
    const float* Wfc1 = (const float*)d_in[8];
    const float* bfc1 = (const float*)d_in[9];
    float* out = (float*)d_out;

    const size_t ND = (size_t)N_NODES * DD;  // 12.8M
    u16* Xb = (u16*)d_ws;
    u16* Hb = Xb + ND;
    u16* Agg = Hb + ND;
    u16* Wpb0 = Agg + ND;
    u16* Wfb0 = Wpb0 + 65536;
    u16* Wpb1 = Wfb0 + 131072;
    u16* Wfb1 = Wpb1 + 65536;

    cvt_w_k<<<32, 256, 0, stream>>>(Wp0, Wpb0, 8);
    cvt_w_k<<<64, 256, 0, stream>>>(Wfc0, Wfb0, 16);
    cvt_w_k<<<32, 256, 0, stream>>>(Wp1, Wpb1, 8);
    cvt_w_k<<<64, 256, 0, stream>>>(Wfc1, Wfb1, 16);
    cvt_f32_bf16_k<<<12500, 256, 0, stream>>>((const float4*)features, Xb);

    dim3 gg((N_NODES + 127) / 128, 2);

    // ---- layer 0 ----
    gemm_k<8, true, true><<<gg, 256, 0, stream>>>(Xb, nullptr, Wpb0, bp0, Hb, nullptr, N_NODES);
    gather_max_k<<<12500, 256, 0, stream>>>(Hb, neigh, Agg);
    gemm_k<16, true, true><<<gg, 256, 0, stream>>>(Xb, Agg, Wfb0, bfc0, Hb, nullptr, N_NODES);

    // ---- layer 1 ----
    gemm_k<8, true, true><<<gg, 256, 0, stream>>>(Hb, nullptr, Wpb1, bp1, Xb, nullptr, N_NODES);
    gather_max_k<<<12500, 256, 0, stream>>>(Xb, neigh, Agg);
    gemm_k<16, false, false><<<gg, 256, 0, stream>>>(Hb, Agg, Wfb1, bfc1, nullptr, out, N_NODES);
}

// Round 3
// 307.722 us; speedup vs baseline: 1.2280x; 1.0675x over previous
//
#include <hip/hip_runtime.h>
#include <stdint.h>

#define N_NODES 50000
#define DD 256
#define SS 25

typedef unsigned short u16;
typedef __attribute__((ext_vector_type(8))) __bf16 bf16x8;
typedef __attribute__((ext_vector_type(4))) float f32x4;

__device__ __forceinline__ float bf2f(u16 u) {
    union { uint32_t i; float f; } c;
    c.i = ((uint32_t)u) << 16;
    return c.f;
}
__device__ __forceinline__ u16 f2bf(float f) {  // round-to-nearest-even
    union { float f; uint32_t i; } c;
    c.f = f;
    uint32_t r = c.i + 0x7fffu + ((c.i >> 16) & 1u);
    return (u16)(r >> 16);
}

__device__ __forceinline__ void gld16(void* lds, const void* g) {
    __builtin_amdgcn_global_load_lds(
        (const __attribute__((address_space(1))) uint32_t*)g,
        (__attribute__((address_space(3))) uint32_t*)lds, 16, 0, 0);
}

// ---- f32 -> bf16 elementwise (exact: grid*block*4 == n) ----
__global__ __launch_bounds__(256) void cvt_f32_bf16_k(const float4* __restrict__ in,
                                                      u16* __restrict__ out) {
    int i = blockIdx.x * 256 + threadIdx.x;
    float4 v = in[i];
    uint2 o;
    o.x = (uint32_t)f2bf(v.x) | ((uint32_t)f2bf(v.y) << 16);
    o.y = (uint32_t)f2bf(v.z) | ((uint32_t)f2bf(v.w) << 16);
    *reinterpret_cast<uint2*>(out + (size_t)i * 4) = o;
}

// ---- weight f32 [K][256] -> bf16 MFMA B-fragment layout ----
// out[((kt*16 + ct)*64 + lane)*8 + e] = W[kt*32 + (lane>>4)*8 + e][ct*16 + (lane&15)]
__global__ __launch_bounds__(256) void cvt_w_k(const float* __restrict__ W,
                                               u16* __restrict__ out, int KT) {
    int t = blockIdx.x * 256 + threadIdx.x;
    if (t >= KT * 16 * 64) return;
    int lane = t & 63;
    int ct = (t >> 6) & 15;
    int kt = t >> 10;
    int k0 = kt * 32 + (lane >> 4) * 8;
    int col = ct * 16 + (lane & 15);
    u16 r[8];
#pragma unroll
    for (int e = 0; e < 8; e++) r[e] = f2bf(W[(size_t)(k0 + e) * DD + col]);
    uint4 v;
    v.x = (uint32_t)r[0] | ((uint32_t)r[1] << 16);
    v.y = (uint32_t)r[2] | ((uint32_t)r[3] << 16);
    v.z = (uint32_t)r[4] | ((uint32_t)r[5] << 16);
    v.w = (uint32_t)r[6] | ((uint32_t)r[7] << 16);
    *reinterpret_cast<uint4*>(out + (size_t)t * 8) = v;
}

// ---- GEMM1: out[M,256] = relu(A @ Bf + bias), bf16 out ----
// 128x128 tile, 4 waves, double-buffered LDS, global_load_lds width 16.
__global__ __launch_bounds__(256) void gemm1_k(const u16* __restrict__ A1,
                                               const u16* __restrict__ Bf,
                                               const float* __restrict__ bias,
                                               u16* __restrict__ obf, int M) {
    __shared__ u16 sAB[2][8192];  // per buf: A [0,4096), B [4096,8192)
    const int lane = threadIdx.x & 63;
    const int w = threadIdx.x >> 6;
    const int wm = w >> 1, wn = w & 1;
    const int row_base = blockIdx.x * 128;
    const int ct0b = blockIdx.y * 8;
    const int lr = lane & 15, lk = lane >> 4;

    f32x4 acc[4][4] = {};

    auto stage = [&](int buf, int kt) {
#pragma unroll
        for (int j = 0; j < 2; ++j) {
            int row = row_base + j * 64 + lane;
            if (row >= M) row = M - 1;
            gld16(&sAB[buf][(w * 2 + j) * 512 + lane * 8],
                  A1 + (size_t)row * DD + kt * 32 + w * 8);
        }
#pragma unroll
        for (int j = 0; j < 2; ++j) {
            const int nl = w * 2 + j;
            gld16(&sAB[buf][4096 + nl * 512 + lane * 8],
                  Bf + ((size_t)(kt * 16 + ct0b + nl) * 64 + lane) * 8);
        }
    };

    auto compute = [&](int buf) {
        bf16x8 a[4], b[4];
#pragma unroll
        for (int m = 0; m < 4; m++)
            a[m] = *reinterpret_cast<const bf16x8*>(
                &sAB[buf][lk * 1024 + (wm * 64 + m * 16 + lr) * 8]);
#pragma unroll
        for (int n = 0; n < 4; n++)
            b[n] = *reinterpret_cast<const bf16x8*>(
                &sAB[buf][4096 + (wn * 4 + n) * 512 + lane * 8]);
#pragma unroll
        for (int m = 0; m < 4; m++)
#pragma unroll
            for (int n = 0; n < 4; n++)
                acc[m][n] = __builtin_amdgcn_mfma_f32_16x16x32_bf16(a[m], b[n], acc[m][n], 0, 0, 0);
    };

    stage(0, 0);
    asm volatile("s_waitcnt vmcnt(0)" ::: "memory");
    __syncthreads();
    int buf = 0;
#pragma unroll
    for (int kt = 0; kt < 7; ++kt) {
        stage(buf ^ 1, kt + 1);
        compute(buf);
        asm volatile("s_waitcnt vmcnt(0)" ::: "memory");
        __syncthreads();
        buf ^= 1;
    }
    compute(buf);

    const int col_base = blockIdx.y * 128 + wn * 64;
#pragma unroll
    for (int n = 0; n < 4; n++) {
        const int col = col_base + n * 16 + lr;
        const float bz = bias[col];
#pragma unroll
        for (int m = 0; m < 4; m++) {
            const int r0 = row_base + wm * 64 + m * 16 + lk * 4;
#pragma unroll
            for (int e = 0; e < 4; e++) {
                const int r = r0 + e;
                if (r < M) obf[(size_t)r * DD + col] = f2bf(fmaxf(acc[m][n][e] + bz, 0.0f));
            }
        }
    }
}

// ---- Fused gather-max + GEMM2 ----
// Per 64-row block: (1) agg[64][256] = max over 25 neighbors of h -> swizzled LDS,
// (2) out = [X | agg] @ Bf + bias. BN=256, 8 waves (wave = 64 rows x 32 cols).
template <bool RELU, bool OUTBF16>
__global__ __launch_bounds__(512) void fused_gemm2_k(const u16* __restrict__ A1,
                                                     const u16* __restrict__ h,
                                                     const int* __restrict__ idx,
                                                     const u16* __restrict__ Bf,
                                                     const float* __restrict__ bias,
                                                     u16* __restrict__ obf,
                                                     float* __restrict__ of32, int M) {
    __shared__ u16 aggT[64 * 256];   // 32KB, chunk-swizzled: [row][ (chunk^(row&7))*8 ]
    __shared__ u16 sX[2][2048];      // X A-tile dbuf: [lk4][64 rows][8] -> 4KB each
    __shared__ u16 sB[2][8192];      // B dbuf: 16 frags x 64 x 8 -> 16KB each
    __shared__ int sidx[64 * SS];    // 6.4KB
    const int tid = threadIdx.x;
    const int lane = tid & 63;
    const int w = tid >> 6;  // 0..7
    const int row_base = blockIdx.x * 64;

    // neighbor indices for this block's 64 nodes
    for (int j = tid; j < 64 * SS; j += 512) {
        int n = row_base + j / SS;
        if (n >= M) n = M - 1;
        sidx[j] = idx[(size_t)n * SS + (j % SS)];
    }
    __syncthreads();

    // issue first K-step staging early (overlaps with gather)
    auto stageX = [&](int buf, int kt) {  // waves 0..3: lk = w
        if (w < 4) {
            int row = row_base + lane;
            if (row >= M) row = M - 1;
            gld16(&sX[buf][w * 512 + lane * 8], A1 + (size_t)row * DD + kt * 32 + w * 8);
        }
    };
    auto stageB = [&](int buf, int kt) {  // 2 frags per wave
#pragma unroll
        for (int j = 0; j < 2; ++j) {
            const int nl = w * 2 + j;
            gld16(&sB[buf][nl * 512 + lane * 8],
                  Bf + ((size_t)(kt * 16 + nl) * 64 + lane) * 8);
        }
    };
    stageX(0, 0);
    stageB(0, 0);

    // ---- gather-max phase: 8 nodes per wave ----
    {
        const int half = lane >> 5;
        const int c8 = lane & 31;  // 16B chunk
        for (int nl = w; nl < 64; nl += 8) {
            float m[8];
#pragma unroll
            for (int j = 0; j < 8; j++) m[j] = 0.0f;  // h >= 0 (relu)
#pragma unroll
            for (int s = 0; s < SS; s += 2) {
                int sp = s + half;
                if (sp >= SS) sp = SS - 1;
                const int r = sidx[nl * SS + sp];
                uint4 v = *reinterpret_cast<const uint4*>(h + (size_t)r * DD + c8 * 8);
                m[0] = fmaxf(m[0], bf2f((u16)(v.x & 0xffffu)));
                m[1] = fmaxf(m[1], bf2f((u16)(v.x >> 16)));
                m[2] = fmaxf(m[2], bf2f((u16)(v.y & 0xffffu)));
                m[3] = fmaxf(m[3], bf2f((u16)(v.y >> 16)));
                m[4] = fmaxf(m[4], bf2f((u16)(v.z & 0xffffu)));
                m[5] = fmaxf(m[5], bf2f((u16)(v.z >> 16)));
                m[6] = fmaxf(m[6], bf2f((u16)(v.w & 0xffffu)));
                m[7] = fmaxf(m[7], bf2f((u16)(v.w >> 16)));
            }
#pragma unroll
            for (int j = 0; j < 8; j++) m[j] = fmaxf(m[j], __shfl_xor(m[j], 32));
            if (half == 0) {
                uint4 o;
                o.x = (uint32_t)f2bf(m[0]) | ((uint32_t)f2bf(m[1]) << 16);
                o.y = (uint32_t)f2bf(m[2]) | ((uint32_t)f2bf(m[3]) << 16);
                o.z = (uint32_t)f2bf(m[4]) | ((uint32_t)f2bf(m[5]) << 16);
                o.w = (uint32_t)f2bf(m[6]) | ((uint32_t)f2bf(m[7]) << 16);
                const int ch = c8 ^ (nl & 7);
                *reinterpret_cast<uint4*>(&aggT[nl * 256 + ch * 8]) = o;
            }
        }
    }

    // ---- GEMM phase: K = 512 (kt 0..7 = X from dbuf, kt 8..15 = agg from LDS) ----
    const int lr = lane & 15, lk = lane >> 4;
    f32x4 acc[4][2] = {};

    auto compute = [&](int buf, int kt) {
        bf16x8 a[4], b[2];
        if (kt < 8) {
#pragma unroll
            for (int m = 0; m < 4; m++)
                a[m] = *reinterpret_cast<const bf16x8*>(
                    &sX[buf][lk * 512 + (m * 16 + lr) * 8]);
        } else {
            const int cb = (kt - 8) * 4 + lk;
#pragma unroll
            for (int m = 0; m < 4; m++) {
                const int row = m * 16 + lr;
                const int ch = cb ^ (row & 7);
                a[m] = *reinterpret_cast<const bf16x8*>(&aggT[row * 256 + ch * 8]);
            }
        }
#pragma unroll
        for (int n = 0; n < 2; n++)
            b[n] = *reinterpret_cast<const bf16x8*>(&sB[buf][(w * 2 + n) * 512 + lane * 8]);
#pragma unroll
        for (int m = 0; m < 4; m++)
#pragma unroll
            for (int n = 0; n < 2; n++)
                acc[m][n] = __builtin_amdgcn_mfma_f32_16x16x32_bf16(a[m], b[n], acc[m][n], 0, 0, 0);
    };

    asm volatile("s_waitcnt vmcnt(0)" ::: "memory");
    __syncthreads();  // agg + first stage ready
    int buf = 0;
#pragma unroll
    for (int kt = 0; kt < 15; ++kt) {
        if (kt + 1 < 8) stageX(buf ^ 1, kt + 1);
        stageB(buf ^ 1, kt + 1);
        compute(buf, kt);
        asm volatile("s_waitcnt vmcnt(0)" ::: "memory");
        __syncthreads();
        buf ^= 1;
    }
    compute(buf, 15);

    // epilogue: wave w owns cols [w*32, w*32+32)
#pragma unroll
    for (int n = 0; n < 2; n++) {
        const int col = w * 32 + n * 16 + lr;
        const float bz = bias[col];
#pragma unroll
        for (int m = 0; m < 4; m++) {
            const int r0 = row_base + m * 16 + lk * 4;
#pragma unroll
            for (int e = 0; e < 4; e++) {
                const int r = r0 + e;
                if (r < M) {
                    float v = acc[m][n][e] + bz;
                    if (RELU) v = fmaxf(v, 0.0f);
                    if (OUTBF16)
                        obf[(size_t)r * DD + col] = f2bf(v);
                    else
                        of32[(size_t)r * DD + col] = v;
                }
            }
        }
    }
}

extern "C" void kernel_launch(void* const* d_in, const int* in_sizes, int n_in,
                              void* d_out, int out_size, void* d_ws, size_t ws_size,
                              hipStream_t stream) {
    const float* features = (const float*)d_in[0];
    const int* neigh = (const int*)d_in[1];
    const float* Wp0 = (const float*)d_in[2];
    const float* bp0 = (const float*)d_in[3];
    const float* Wfc0 = (const float*)d_in[4];
    const float* bfc0 = (const float*)d_in[5];
    const float* Wp1 = (const float*)d_in[6];
    const float* bp1 = (const float*)d_in[7];
    const float* Wfc1 = (const float*)d_in[8];
    const float* bfc1 = (const float*)d_in[9];
    float* out = (float*)d_out;

    const size_t ND = (size_t)N_NODES * DD;  // 12.8M
    u16* Xb = (u16*)d_ws;     // features bf16; later reused for h1
    u16* Hb = Xb + ND;        // h0
    u16* O0 = Hb + ND;        // layer-0 output
    u16* Wpb0 = O0 + ND;
    u16* Wfb0 = Wpb0 + 65536;
    u16* Wpb1 = Wfb0 + 131072;
    u16* Wfb1 = Wpb1 + 65536;

    cvt_w_k<<<32, 256, 0, stream>>>(Wp0, Wpb0, 8);
    cvt_w_k<<<64, 256, 0, stream>>>(Wfc0, Wfb0, 16);
    cvt_w_k<<<32, 256, 0, stream>>>(Wp1, Wpb1, 8);
    cvt_w_k<<<64, 256, 0, stream>>>(Wfc1, Wfb1, 16);
    cvt_f32_bf16_k<<<12500, 256, 0, stream>>>((const float4*)features, Xb);

    dim3 g1((N_NODES + 127) / 128, 2);
    const int gf = (N_NODES + 63) / 64;  // 782

    // ---- layer 0 ----
    gemm1_k<<<g1, 256, 0, stream>>>(Xb, Wpb0, bp0, Hb, N_NODES);
    fused_gemm2_k<true, true><<<gf, 512, 0, stream>>>(Xb, Hb, neigh, Wfb0, bfc0, O0, nullptr, N_NODES);

    // ---- layer 1 ---- (Xb dead -> reuse for h1)
    gemm1_k<<<g1, 256, 0, stream>>>(O0, Wpb1, bp1, Xb, N_NODES);
    fused_gemm2_k<false, false><<<gf, 512, 0, stream>>>(O0, Xb, neigh, Wfb1, bfc1, nullptr, out, N_NODES);
}